// Round 2
// baseline (663.304 us; speedup 1.0000x reference)
//
#include <hip/hip_runtime.h>
#include <hip/hip_bf16.h>
#include <math.h>

#define B_ 32
#define S_ 128
#define C_ 384
#define H_ 8
#define W_ 512
#define NKV 4096   // H_*W_

typedef __attribute__((ext_vector_type(8))) short short8;
typedef __attribute__((ext_vector_type(4))) float floatx4;

static __device__ __forceinline__ ushort f2bf(float v) {
    __hip_bfloat16 h = __float2bfloat16(v);
    return *(ushort*)&h;
}
static __device__ __forceinline__ float ldf(const float* p, size_t i) { return p[i]; }
static __device__ __forceinline__ float ldf(const ushort* p, size_t i) {
    union { uint u; float f; } c; c.u = (uint)p[i] << 16; return c.f;
}

// async global->LDS, 16B per lane (wave-uniform base + lane*16 — LDS layout linear in tid)
static __device__ __forceinline__ void gl_lds16(const ushort* g, ushort* l) {
    __builtin_amdgcn_global_load_lds(
        (const __attribute__((address_space(1))) void*)g,
        (__attribute__((address_space(3))) void*)l, 16, 0, 0);
}

// ---------------------------------------------------------------- mean over H -> bf16
__global__ __launch_bounds__(256) void mean_kernel(const float* __restrict__ kv,
                                                   ushort* __restrict__ dec0b) {
    int v = blockIdx.x * blockDim.x + threadIdx.x;  // float4 index over (B,W,C)
    int total = B_ * W_ * (C_ / 4);
    if (v >= total) return;
    int c4  = v % (C_ / 4);
    int row = v / (C_ / 4);      // b*W + w
    int b = row / W_;
    int w = row % W_;
    const float4* src = (const float4*)kv + (size_t)(b * NKV + w) * (C_ / 4) + c4;
    float4 s = {0.f, 0.f, 0.f, 0.f};
#pragma unroll
    for (int h = 0; h < H_; ++h) {
        float4 t = src[(size_t)h * W_ * (C_ / 4)];
        s.x += t.x; s.y += t.y; s.z += t.z; s.w += t.w;
    }
    ushort4 o;
    o.x = f2bf(s.x * 0.125f); o.y = f2bf(s.y * 0.125f);
    o.z = f2bf(s.z * 0.125f); o.w = f2bf(s.w * 0.125f);
    ((ushort4*)dec0b)[v] = o;
}

// ---------------------------------------------------------------- cast fp32 -> bf16
__global__ __launch_bounds__(256) void cast_kernel(const float* __restrict__ in,
                                                   ushort* __restrict__ out, int n4) {
    int v = blockIdx.x * blockDim.x + threadIdx.x;
    if (v >= n4) return;
    float4 f = ((const float4*)in)[v];
    ushort4 o;
    o.x = f2bf(f.x); o.y = f2bf(f.y); o.z = f2bf(f.z); o.w = f2bf(f.w);
    ((ushort4*)out)[v] = o;
}

// ------------------------------------------------- weight transpose+cast (K,N)->(N,K)
// 32x32 LDS tiles: coalesced float4 reads of src rows, bf16 ushort4 writes of dst rows.
struct WtDesc { const float* src[12]; ushort* dst[12]; int Kd[12]; int Nd[12]; };
__global__ __launch_bounds__(256) void wtcast_kernel(WtDesc d) {
    int wi = blockIdx.y;
    int K = d.Kd[wi], N = d.Nd[wi];
    int tiles_n = N / 32;
    int tile = blockIdx.x;
    if (tile >= (K / 32) * tiles_n) return;
    int k0 = (tile / tiles_n) * 32, n0 = (tile % tiles_n) * 32;
    __shared__ float t[32][33];
    int tid = threadIdx.x;
    int r = tid >> 3, c4 = (tid & 7) * 4;
    float4 v = *(const float4*)&d.src[wi][(size_t)(k0 + r) * N + n0 + c4];
    t[r][c4] = v.x; t[r][c4 + 1] = v.y; t[r][c4 + 2] = v.z; t[r][c4 + 3] = v.w;
    __syncthreads();
    int c = tid >> 3, k4 = (tid & 7) * 4;
    ushort4 o;
    o.x = f2bf(t[k4][c]); o.y = f2bf(t[k4 + 1][c]);
    o.z = f2bf(t[k4 + 2][c]); o.w = f2bf(t[k4 + 3][c]);
    *(ushort4*)&d.dst[wi][(size_t)(n0 + c) * K + k0 + k4] = o;
}

// ---------------------------------------------------------------- bf16 MFMA GEMM 128x128
// m97 structure: linear LDS [128][32] ushort, global_load_lds dwordx4 staging,
// 2-barrier K-loop.
__global__ __launch_bounds__(256) void bgemm_kernel(
    const ushort* __restrict__ A, const ushort* __restrict__ Bt,
    const float* __restrict__ bias, float* __restrict__ Cout,
    ushort* __restrict__ Cbf, int M, int N, int K, float alpha, int act)
{
    __shared__ ushort As[128 * 32];
    __shared__ ushort Bs[128 * 32];
    const int tid = threadIdx.x;
    const int bm = blockIdx.y * 128, bn = blockIdx.x * 128;
    const int wav = tid >> 6, lane = tid & 63;
    const int wm = (wav >> 1) * 64, wn = (wav & 1) * 64;
    const int lrow = lane & 15, lq = lane >> 4;

    floatx4 acc[4][4] = {};

    const int crow = tid >> 2, ccol = (tid & 3) * 8;
    const ushort* Ag0 = A + (size_t)(bm + crow) * K + ccol;
    const ushort* Ag1 = Ag0 + (size_t)64 * K;
    const ushort* Bg0 = Bt + (size_t)(bn + crow) * K + ccol;
    const ushort* Bg1 = Bg0 + (size_t)64 * K;
    ushort* AsP0 = &As[tid * 8];
    ushort* AsP1 = &As[2048 + tid * 8];
    ushort* BsP0 = &Bs[tid * 8];
    ushort* BsP1 = &Bs[2048 + tid * 8];

    for (int k0 = 0; k0 < K; k0 += 32) {
        gl_lds16(Ag0 + k0, AsP0);
        gl_lds16(Ag1 + k0, AsP1);
        gl_lds16(Bg0 + k0, BsP0);
        gl_lds16(Bg1 + k0, BsP1);
        __syncthreads();          // drains vmcnt -> tiles resident
        short8 af[4], bfr[4];
#pragma unroll
        for (int i = 0; i < 4; ++i)
            af[i] = *(const short8*)&As[(wm + 16 * i + lrow) * 32 + lq * 8];
#pragma unroll
        for (int j = 0; j < 4; ++j)
            bfr[j] = *(const short8*)&Bs[(wn + 16 * j + lrow) * 32 + lq * 8];
#pragma unroll
        for (int i = 0; i < 4; ++i)
#pragma unroll
            for (int j = 0; j < 4; ++j)
                acc[i][j] = __builtin_amdgcn_mfma_f32_16x16x32_bf16(af[i], bfr[j], acc[i][j], 0, 0, 0);
        __syncthreads();          // all waves done reading before next overwrite
    }

#pragma unroll
    for (int i = 0; i < 4; ++i)
#pragma unroll
        for (int j = 0; j < 4; ++j) {
            int row = bm + wm + 16 * i + lq * 4;
            int col = bn + wn + 16 * j + lrow;
            float bv = bias ? bias[col] : 0.f;
#pragma unroll
            for (int r = 0; r < 4; ++r) {
                float v = acc[i][j][r] * alpha + bv;
                if (act == 1) v = tanhf(v);
                size_t off = (size_t)(row + r) * N + col;
                if (Cout) Cout[off] = v;
                if (Cbf) Cbf[off] = f2bf(v);
            }
        }
}

static inline void bgemm(hipStream_t st, const ushort* A, const ushort* Bt,
                         const float* bias, float* Cout, ushort* Cbf,
                         int M, int N, int K, float alpha, int act) {
    dim3 grid(N / 128, M / 128), block(256);
    bgemm_kernel<<<grid, block, 0, st>>>(A, Bt, bias, Cout, Cbf, M, N, K, alpha, act);
}

// ------------------------------------------- generic batched 128x64 MFMA GEMM
struct BGArgs {
    const ushort* A; const ushort* Bt;
    const float* bias; float* outF; ushort* outB;
    int lda, ldb, ldo;
    long AsB, BsB, OsB;
    int AsH, BsH, OsH;
    int K, NH;
    float alpha; int act;
};
__global__ __launch_bounds__(256) void battn_kernel(BGArgs g) {
    __shared__ ushort As[128 * 40];
    __shared__ ushort Bs[64 * 40];
    const int bn = blockIdx.x * 64, bm = blockIdx.y * 128;
    const int bat = blockIdx.z, bb = bat / g.NH, hh = bat % g.NH;
    const ushort* A  = g.A  + (size_t)bb * g.AsB + (size_t)hh * g.AsH;
    const ushort* Bt = g.Bt + (size_t)bb * g.BsB + (size_t)hh * g.BsH;
    const int tid = threadIdx.x;
    const int wav = tid >> 6, lane = tid & 63;
    const int lrow = lane & 15, lq = lane >> 4;
    const int sr = tid >> 2, sc0 = (tid & 3) * 8;
    const ushort* Ag0 = A + (size_t)(bm + sr) * g.lda + sc0;
    const ushort* Ag1 = A + (size_t)(bm + sr + 64) * g.lda + sc0;
    const ushort* Bg  = Bt + (size_t)(bn + sr) * g.ldb + sc0;
    ushort* Asw0 = &As[sr * 40 + sc0];
    ushort* Asw1 = &As[(sr + 64) * 40 + sc0];
    ushort* Bsw  = &Bs[sr * 40 + sc0];

    floatx4 acc[2][4] = {};

    for (int k0 = 0; k0 < g.K; k0 += 32) {
        uint4 a0 = *(const uint4*)(Ag0 + k0);
        uint4 a1 = *(const uint4*)(Ag1 + k0);
        uint4 b  = *(const uint4*)(Bg + k0);
        __syncthreads();
        *(uint4*)Asw0 = a0; *(uint4*)Asw1 = a1; *(uint4*)Bsw = b;
        __syncthreads();
        short8 af0 = *(const short8*)&As[(wav * 32 + lrow) * 40 + lq * 8];
        short8 af1 = *(const short8*)&As[(wav * 32 + 16 + lrow) * 40 + lq * 8];
#pragma unroll
        for (int j = 0; j < 4; ++j) {
            short8 bf = *(const short8*)&Bs[(16 * j + lrow) * 40 + lq * 8];
            acc[0][j] = __builtin_amdgcn_mfma_f32_16x16x32_bf16(af0, bf, acc[0][j], 0, 0, 0);
            acc[1][j] = __builtin_amdgcn_mfma_f32_16x16x32_bf16(af1, bf, acc[1][j], 0, 0, 0);
        }
    }

#pragma unroll
    for (int i = 0; i < 2; ++i)
#pragma unroll
        for (int j = 0; j < 4; ++j) {
            int col = bn + 16 * j + lrow;
            float bv = g.bias ? g.bias[col] : 0.f;
            int row0 = bm + wav * 32 + 16 * i + lq * 4;
#pragma unroll
            for (int r = 0; r < 4; ++r) {
                float v = acc[i][j][r] * g.alpha + bv;
                if (g.act == 1) v = tanhf(v);
                size_t off = (size_t)bb * g.OsB + (size_t)hh * g.OsH
                           + (size_t)(row0 + r) * g.ldo + col;
                if (g.outF) g.outF[off] = v;
                if (g.outB) g.outB[off] = f2bf(v);
            }
        }
}

static inline void battn(hipStream_t st, const ushort* A, const ushort* Bt,
                         const float* bias, float* outF, ushort* outB,
                         int M, int N, int K, float alpha, int act,
                         int lda, long AsB, int AsH,
                         int ldb, long BsB, int BsH,
                         int ldo, long OsB, int OsH,
                         int NH, int nbat) {
    BGArgs g;
    g.A = A; g.Bt = Bt; g.bias = bias; g.outF = outF; g.outB = outB;
    g.lda = lda; g.ldb = ldb; g.ldo = ldo;
    g.AsB = AsB; g.BsB = BsB; g.OsB = OsB;
    g.AsH = AsH; g.BsH = BsH; g.OsH = OsH;
    g.K = K; g.NH = NH; g.alpha = alpha; g.act = act;
    dim3 grid(N / 64, M / 128, nbat);
    battn_kernel<<<grid, 256, 0, st>>>(g);
}

static inline void bgemm64(hipStream_t st, const ushort* A, const ushort* Bt,
                           const float* bias, float* outF, ushort* outB,
                           int M, int N, int K, float alpha, int act) {
    battn(st, A, Bt, bias, outF, outB, M, N, K, alpha, act,
          K, 0, 0, K, 0, 0, N, 0, 0, 1, 1);
}

// ------------------------------------------- fused QK^T (+gauss) + softmax -> P bf16
// One block = (b, h, MT q-rows). Q tile + per-chunk K tile staged in LDS; scores stay
// in MFMA accumulators; softmax row-reduce: 16-lane shfl groups + cross-wave LDS.
// Wave w owns kv-cols {64c + 16w + (lane&15)}; rows m = 16mi + lq*4 + r (battn mapping).
template <int NW, int HD, int MT, int GAUSS, int NH>
__global__ __launch_bounds__(256) void attn_sm_kernel(
    const ushort* __restrict__ Q, const ushort* __restrict__ Kt,
    const float* __restrict__ ptv, ushort* __restrict__ P)
{
    constexpr int NC = NW / 64, MF = MT / 16, KS = HD / 32;
    constexpr int HDP = HD + 8, NWP = NW + 8;
    __shared__ ushort Qs[MT * HDP];
    __shared__ ushort Ks[64 * HDP];
    __shared__ ushort Ps[MT * NWP];
    __shared__ float redm[4][MT];
    __shared__ float reds[4][MT];
    __shared__ float pts[MT];

    const int tid = threadIdx.x;
    const int wav = tid >> 6, lane = tid & 63;
    const int lrow = lane & 15, lq = lane >> 4;
    const int z = blockIdx.z, b = z / NH, hh = z % NH;
    const int mt0 = blockIdx.x * MT;

    // stage Q tile [MT][HD]
    const ushort* Qg = Q + ((size_t)b * S_ + mt0) * C_ + hh * HD;
    for (int i = tid; i < MT * (HD / 8); i += 256) {
        int m = i / (HD / 8), c8 = (i % (HD / 8)) * 8;
        *(uint4*)&Qs[m * HDP + c8] = *(const uint4*)&Qg[(size_t)m * C_ + c8];
    }
    if (GAUSS && tid < MT) pts[tid] = ptv[(size_t)z * S_ + mt0 + tid];
    __syncthreads();

    short8 qreg[KS][MF];
#pragma unroll
    for (int ks = 0; ks < KS; ++ks)
#pragma unroll
        for (int mi = 0; mi < MF; ++mi)
            qreg[ks][mi] = *(const short8*)&Qs[(16 * mi + lrow) * HDP + ks * 32 + lq * 8];

    floatx4 acc[NC][MF] = {};
    const ushort* Kg = Kt + (size_t)b * NW * 768 + hh * HD;
    for (int c = 0; c < NC; ++c) {
        __syncthreads();   // previous chunk fully consumed
        for (int i = tid; i < 64 * (HD / 8); i += 256) {
            int n = i / (HD / 8), c8 = (i % (HD / 8)) * 8;
            *(uint4*)&Ks[n * HDP + c8] = *(const uint4*)&Kg[(size_t)(64 * c + n) * 768 + c8];
        }
        __syncthreads();
#pragma unroll
        for (int ks = 0; ks < KS; ++ks) {
            short8 kf = *(const short8*)&Ks[(16 * wav + lrow) * HDP + ks * 32 + lq * 8];
#pragma unroll
            for (int mi = 0; mi < MF; ++mi)
                acc[c][mi] = __builtin_amdgcn_mfma_f32_16x16x32_bf16(qreg[ks][mi], kf, acc[c][mi], 0, 0, 0);
        }
    }

    // gauss (pre-softmax, multiplicative on scores) + row max
    float pl[MF][4];
    if (GAUSS) {
#pragma unroll
        for (int mi = 0; mi < MF; ++mi)
#pragma unroll
            for (int r = 0; r < 4; ++r) pl[mi][r] = pts[16 * mi + lq * 4 + r];
    }
    float mrow[MF][4];
#pragma unroll
    for (int mi = 0; mi < MF; ++mi)
#pragma unroll
        for (int r = 0; r < 4; ++r) mrow[mi][r] = -1e30f;
#pragma unroll
    for (int c = 0; c < NC; ++c)
#pragma unroll
        for (int mi = 0; mi < MF; ++mi)
#pragma unroll
            for (int r = 0; r < 4; ++r) {
                float v = acc[c][mi][r];
                if (GAUSS) {
                    float dw = (float)(64 * c + 16 * wav + lrow) - pl[mi][r];
                    v *= expf(dw * dw * (-1.0f / 18.0f));
                    acc[c][mi][r] = v;
                }
                mrow[mi][r] = fmaxf(mrow[mi][r], v);
            }
#pragma unroll
    for (int o = 1; o < 16; o <<= 1)
#pragma unroll
        for (int mi = 0; mi < MF; ++mi)
#pragma unroll
            for (int r = 0; r < 4; ++r)
                mrow[mi][r] = fmaxf(mrow[mi][r], __shfl_xor(mrow[mi][r], o));
    if (lrow == 0)
#pragma unroll
        for (int mi = 0; mi < MF; ++mi)
#pragma unroll
            for (int r = 0; r < 4; ++r) redm[wav][16 * mi + lq * 4 + r] = mrow[mi][r];
    __syncthreads();
#pragma unroll
    for (int mi = 0; mi < MF; ++mi)
#pragma unroll
        for (int r = 0; r < 4; ++r) {
            int m = 16 * mi + lq * 4 + r;
            mrow[mi][r] = fmaxf(fmaxf(redm[0][m], redm[1][m]), fmaxf(redm[2][m], redm[3][m]));
        }
    // exp + row sum
    float srow[MF][4] = {};
#pragma unroll
    for (int c = 0; c < NC; ++c)
#pragma unroll
        for (int mi = 0; mi < MF; ++mi)
#pragma unroll
            for (int r = 0; r < 4; ++r) {
                float e = expf(acc[c][mi][r] - mrow[mi][r]);
                acc[c][mi][r] = e;
                srow[mi][r] += e;
            }
#pragma unroll
    for (int o = 1; o < 16; o <<= 1)
#pragma unroll
        for (int mi = 0; mi < MF; ++mi)
#pragma unroll
            for (int r = 0; r < 4; ++r) srow[mi][r] += __shfl_xor(srow[mi][r], o);
    if (lrow == 0)
#pragma unroll
        for (int mi = 0; mi < MF; ++mi)
#pragma unroll
            for (int r = 0; r < 4; ++r) reds[wav][16 * mi + lq * 4 + r] = srow[mi][r];
    __syncthreads();
#pragma unroll
    for (int mi = 0; mi < MF; ++mi)
#pragma unroll
        for (int r = 0; r < 4; ++r) {
            int m = 16 * mi + lq * 4 + r;
            float s = reds[0][m] + reds[1][m] + reds[2][m] + reds[3][m];
            float rinv = 1.0f / s;
#pragma unroll
            for (int c = 0; c < NC; ++c)
                Ps[m * NWP + 64 * c + 16 * wav + lrow] = f2bf(acc[c][mi][r] * rinv);
        }
    __syncthreads();
    // cooperative vectorized P write
    ushort* Pg = P + ((size_t)z * S_ + mt0) * NW;
    for (int i = tid; i < MT * (NW / 8); i += 256) {
        int m = i / (NW / 8), c8 = (i % (NW / 8)) * 8;
        *(uint4*)&Pg[(size_t)m * NW + c8] = *(const uint4*)&Ps[m * NWP + c8];
    }
}

// ---------------------------------------------------------------- dual LayerNorm -> bf16
struct Ln2Desc {
    const void* X0; const float* g0; const float* b0; ushort* Y0; int bf0; int rows0;
    const void* X1; const float* g1; const float* b1; ushort* Y1; int bf1;
};
__global__ __launch_bounds__(128) void ln2_kernel(Ln2Desc d) {
    int row = blockIdx.x;
    const void* X; const float* g; const float* bb; ushort* Y; int isbf;
    if (row < d.rows0) { X = d.X0; g = d.g0; bb = d.b0; Y = d.Y0; isbf = d.bf0; }
    else { row -= d.rows0; X = d.X1; g = d.g1; bb = d.b1; Y = d.Y1; isbf = d.bf1; }
    const float*  xf = (const float*)X + (size_t)row * C_;
    const ushort* xb = (const ushort*)X + (size_t)row * C_;
    ushort* y = Y + (size_t)row * C_;
    int t = threadIdx.x;
    float v0, v1, v2;
    if (isbf) { v0 = ldf(xb, t); v1 = ldf(xb, t + 128); v2 = ldf(xb, t + 256); }
    else      { v0 = ldf(xf, t); v1 = ldf(xf, t + 128); v2 = ldf(xf, t + 256); }
    float s = v0 + v1 + v2, sq = v0 * v0 + v1 * v1 + v2 * v2;
    __shared__ float rs[128], rq[128];
    rs[t] = s; rq[t] = sq; __syncthreads();
    if (t < 64) {
        s = rs[t] + rs[t + 64]; sq = rq[t] + rq[t + 64];
        for (int o = 32; o; o >>= 1) { s += __shfl_down(s, o); sq += __shfl_down(sq, o); }
        if (t == 0) { rs[0] = s; rq[0] = sq; }
    }
    __syncthreads();
    float mean = rs[0] * (1.0f / C_);
    float var  = rq[0] * (1.0f / C_) - mean * mean;
    float inv  = rsqrtf(var + 1e-6f);
    y[t]       = f2bf((v0 - mean) * inv * g[t]       + bb[t]);
    y[t + 128] = f2bf((v1 - mean) * inv * g[t + 128] + bb[t + 128]);
    y[t + 256] = f2bf((v2 - mean) * inv * g[t + 256] + bb[t + 256]);
}

// ------------------------------------------- v transpose: kvb (B*Nw, C2) bf16
__global__ __launch_bounds__(256) void vtrans_kernel(
    const ushort* __restrict__ kvb, ushort* __restrict__ vt,
    int Nw, int C2, int CC)
{
    int b = blockIdx.z;
    int w0 = blockIdx.x * 32, c0 = blockIdx.y * 32;
    __shared__ ushort t[32][33];
    int tid = threadIdx.x;
    int wl = tid >> 3, c4 = (tid & 7) * 4;
    ushort4 v = *(const ushort4*)&kvb[((size_t)b * Nw + w0 + wl) * C2 + CC + c0 + c4];
    t[wl][c4] = v.x; t[wl][c4 + 1] = v.y; t[wl][c4 + 2] = v.z; t[wl][c4 + 3] = v.w;
    __syncthreads();
    int dl = tid >> 3, w4 = (tid & 7) * 4;
    ushort4 o;
    o.x = t[w4][dl]; o.y = t[w4 + 1][dl]; o.z = t[w4 + 2][dl]; o.w = t[w4 + 3][dl];
    *(ushort4*)&vt[((size_t)b * CC + c0 + dl) * Nw + w0 + w4] = o;
}

// ---------------------------------------------------------------- p_t head
__global__ __launch_bounds__(128) void pt_kernel(const float* __restrict__ T,
    const float* __restrict__ vpw, const float* __restrict__ vpb,
    float* __restrict__ out) {
    int row = blockIdx.x;
    int t = threadIdx.x;
    const float* x = T + (size_t)row * C_;
    float s = x[t] * vpw[t] + x[t + 128] * vpw[t + 128] + x[t + 256] * vpw[t + 256];
    __shared__ float red[128];
    red[t] = s; __syncthreads();
    if (t < 64) {
        s = red[t] + red[t + 64];
        for (int o = 32; o; o >>= 1) s += __shfl_down(s, o);
        if (t == 0) {
            float z = s + vpb[0];
            out[row] = 512.0f / (1.0f + expf(-z));
        }
    }
}

// ---------------------------------------------------------------- launch
extern "C" void kernel_launch(void* const* d_in, const int* in_sizes, int n_in,
                              void* d_out, int out_size, void* d_ws, size_t ws_size,
                              hipStream_t stream) {
    const float* q     = (const float*)d_in[0];
    const float* kv    = (const float*)d_in[1];
    const float* Wq    = (const float*)d_in[2];
    const float* Wkv   = (const float*)d_in[3];
    const float* Wproj = (const float*)d_in[4];
    const float* bproj = (const float*)d_in[5];
    const float* Wp_w  = (const float*)d_in[6];
    const float* Wp_b  = (const float*)d_in[7];
    const float* vp_w  = (const float*)d_in[8];
    const float* vp_b  = (const float*)d_in[9];
    const float* Wqpos = (const float*)d_in[10];
    const float* bqpos = (const float*)d_in[11];
    const float* Wrctc = (const float*)d_in[12];
    const float* brctc = (const float*)d_in[13];
    const float* ca1_Wq    = (const float*)d_in[14];
    const float* ca1_Wkv   = (const float*)d_in[15];
    const float* ca1_Wproj = (const float*)d_in[16];
    const float* ca1_bproj = (const float*)d_in[17];
    const float* ca2_Wq    = (const float*)d_in[18];
    const float* ca2_Wkv   = (const float*)d_in[19];
    const float* ca2_Wproj = (const float*)d_in[20];
    const float* ca2_bproj = (const float*)d_in[21];
    const float* g_q1  = (const float*)d_in[22];
    const float* b_q1  = (const float*)d_in[23];
    const float* g_kv1 = (const float*)d_in[24];
    const float* b_kv1 = (const float*)d_in[25];
    const float* g_q2  = (const float*)d_in[26];
    const float* b_q2  = (const float*)d_in[27];
    const float* g_kv2 = (const float*)d_in[28];
    const float* b_kv2 = (const float*)d_in[29];
    float* out = (float*)d_out;
    float* ws  = (float*)d_ws;

    // workspace layout (float offsets) — unchanged from previous round; sc slot now unused
    ushort* dec0b = (ushort*)(ws);                   // 6291456 ush
    ushort* wb    = (ushort*)(ws + 3145728);         // 2211840 ush
    ushort* qb    = (ushort*)(ws + 4251648);         // 1572864 ush
    ushort* decb  = (ushort*)(ws + 5038080);         // 6291456 ush
    ushort* qhb   = (ushort*)(ws + 8183808);         // 1572864 ush
    float*  p     = ws + 8970240;                    // 1572864 fl
    ushort* pb    = (ushort*)(ws + 10543104);        // 1572864 ush
    float*  t1    = ws + 11329536;                   // 1572864 fl
    ushort* t1b   = (ushort*)(ws + 12902400);        // 1572864 ush
    ushort* t2b   = (ushort*)(ws + 13688832);        // 6291456 ush
    ushort* qpb   = (ushort*)(ws + 16834560);        // 1572864 ush
    ushort* kvb   = (ushort*)(ws + 17620992);        // 12582912 ush
    ushort* vt    = (ushort*)(ws + 23912448);        // 6291456 ush
    ushort* Pb    = (ushort*)(ws + 31252480);        // 4194304 ush
    ushort* xb    = (ushort*)(ws + 33349632);        // 1572864 ush
    float*  ptb   = ws + 34136064;                   // 4096 fl

    // bf16 transposed weight sub-offsets (ushort units)
    ushort* wbWq     = wb;
    ushort* wbWqpos  = wb + 147456;
    ushort* wbWrctc  = wb + 294912;
    ushort* wbC1Wq   = wb + 442368;
    ushort* wbC1Wp   = wb + 589824;
    ushort* wbC2Wq   = wb + 737280;
    ushort* wbC2Wp   = wb + 884736;
    ushort* wbWpw    = wb + 1032192;
    ushort* wbWproj  = wb + 1179648;
    ushort* wbWkv    = wb + 1327104;
    ushort* wbC1Wkv  = wb + 1622016;
    ushort* wbC2Wkv  = wb + 1916928;

    const float rs384 = 0.05103103630798288f;  // 1/sqrt(384)
    const float rs192 = 0.07216878364870323f;  // 1/sqrt(192)

    // 1. mean over H -> bf16
    mean_kernel<<<(B_ * W_ * (C_ / 4) + 255) / 256, 256, 0, stream>>>(kv, dec0b);
    // 2. weight transpose-casts + q cast
    {
        WtDesc d;
        const float* s_[12] = {Wq, Wqpos, Wrctc, ca1_Wq, ca1_Wproj, ca2_Wq, ca2_Wproj,
                               Wp_w, Wproj, Wkv, ca1_Wkv, ca2_Wkv};
        ushort* t_[12] = {wbWq, wbWqpos, wbWrctc, wbC1Wq, wbC1Wp, wbC2Wq, wbC2Wp,
                          wbWpw, wbWproj, wbWkv, wbC1Wkv, wbC2Wkv};
        for (int i = 0; i < 12; ++i) {
            d.src[i] = s_[i]; d.dst[i] = t_[i];
            d.Kd[i] = 384; d.Nd[i] = (i >= 9) ? 768 : 384;
        }
        dim3 grid(288, 12);   // max (K/32)*(N/32) = 12*24
        wtcast_kernel<<<grid, 256, 0, stream>>>(d);
        cast_kernel<<<(393216 + 255) / 256, 256, 0, stream>>>(q, qb, 393216);
    }
    // 3. dec = dec0 @ Wrctc + brctc -> bf16 only
    bgemm(stream, dec0b, wbWrctc, brctc, nullptr, decb, B_ * W_, 384, 384, 1.f, 0);
    // 4. qh bf16 = (q @ Wq)*rs384 ; p fp32 = q @ Wqpos + bqpos
    bgemm64(stream, qb, wbWq, nullptr, nullptr, qhb, B_ * S_, 384, 384, rs384, 0);
    bgemm64(stream, qb, wbWqpos, bqpos, p, nullptr, B_ * S_, 384, 384, 1.f, 0);
    // 5. ca1
    {
        Ln2Desc d;
        d.X0 = p; d.g0 = g_q1;  d.b0 = b_q1;  d.Y0 = t1b; d.bf0 = 0; d.rows0 = B_ * S_;
        d.X1 = q; d.g1 = g_kv1; d.b1 = b_kv1; d.Y1 = t2b; d.bf1 = 0;
        ln2_kernel<<<2 * B_ * S_, 128, 0, stream>>>(d);
    }
    bgemm64(stream, t1b, wbC1Wq, nullptr, nullptr, qpb, B_ * S_, 384, 384, rs192, 0);
    bgemm64(stream, t2b, wbC1Wkv, nullptr, nullptr, kvb, B_ * S_, 768, 384, 1.f, 0);
    {
        dim3 gt(S_ / 32, C_ / 32, B_);
        vtrans_kernel<<<gt, 256, 0, stream>>>(kvb, vt, S_, 768, 384);
    }
    attn_sm_kernel<128, 192, 32, 0, 2><<<dim3(S_ / 32, 1, B_ * 2), 256, 0, stream>>>(
        qpb, kvb, nullptr, Pb);
    battn(stream, Pb, vt, nullptr, nullptr, xb, 128, 192, 128, 1.f, 0,
          128, (long)2 * S_ * 128, S_ * 128,
          128, (long)C_ * S_, 192 * S_,
          384, (long)S_ * 384, 192, 2, 64);
    bgemm64(stream, xb, wbC1Wp, ca1_bproj, p, nullptr, B_ * S_, 384, 384, 1.f, 0);
    // 6. ca2
    {
        Ln2Desc d;
        d.X0 = p;    d.g0 = g_q2;  d.b0 = b_q2;  d.Y0 = t1b; d.bf0 = 0; d.rows0 = B_ * S_;
        d.X1 = decb; d.g1 = g_kv2; d.b1 = b_kv2; d.Y1 = t2b; d.bf1 = 1;
        ln2_kernel<<<B_ * S_ + B_ * W_, 128, 0, stream>>>(d);
    }
    bgemm64(stream, t1b, wbC2Wq, nullptr, nullptr, qpb, B_ * S_, 384, 384, rs192, 0);
    bgemm(stream, t2b, wbC2Wkv, nullptr, nullptr, kvb, B_ * W_, 768, 384, 1.f, 0);
    {
        dim3 gt(W_ / 32, C_ / 32, B_);
        vtrans_kernel<<<gt, 256, 0, stream>>>(kvb, vt, W_, 768, 384);
    }
    attn_sm_kernel<512, 192, 32, 0, 2><<<dim3(S_ / 32, 1, B_ * 2), 256, 0, stream>>>(
        qpb, kvb, nullptr, Pb);
    battn(stream, Pb, vt, nullptr, nullptr, xb, 128, 192, 512, 1.f, 0,
          512, (long)2 * S_ * 512, S_ * 512,
          512, (long)C_ * W_, 192 * W_,
          384, (long)S_ * 384, 192, 2, 64);
    bgemm64(stream, xb, wbC2Wp, ca2_bproj, p, pb, B_ * S_, 384, 384, 1.f, 0);
    // 7. p_t head
    bgemm64(stream, pb, wbWpw, Wp_b, t1, nullptr, B_ * S_, 384, 384, 1.f, 1);
    pt_kernel<<<B_ * S_, 128, 0, stream>>>(t1, vp_w, vp_b, ptb);
    // 8. main k/v = dec @ Wkv -> bf16
    bgemm(stream, decb, wbWkv, nullptr, nullptr, kvb, B_ * W_, 768, 384, 1.f, 0);
    {
        dim3 gt(W_ / 32, C_ / 32, B_);
        vtrans_kernel<<<gt, 256, 0, stream>>>(kvb, vt, W_, 768, 384);
    }
    // 9. main attention: fused scores + gauss + softmax, then PV
    attn_sm_kernel<512, 384, 16, 1, 1><<<dim3(S_ / 16, 1, B_), 256, 0, stream>>>(
        qhb, kvb, ptb, Pb);
    battn(stream, Pb, vt, nullptr, nullptr, xb, 128, 384, 512, 1.f, 0,
          512, (long)S_ * 512, 0,
          512, (long)C_ * W_, 0,
          384, (long)S_ * 384, 0, 1, 32);
    // 10. out = x @ Wproj + bproj (fp32)
    bgemm64(stream, xb, wbWproj, bproj, out, nullptr, B_ * S_, 384, 384, 1.f, 0);
}

// Round 3
// 586.703 us; speedup vs baseline: 1.1306x; 1.1306x over previous
//
#include <hip/hip_runtime.h>
#include <hip/hip_bf16.h>
#include <math.h>

#define B_ 32
#define S_ 128
#define C_ 384
#define H_ 8
#define W_ 512
#define NKV 4096   // H_*W_

typedef __attribute__((ext_vector_type(8))) short short8;
typedef __attribute__((ext_vector_type(4))) float floatx4;

static __device__ __forceinline__ ushort f2bf(float v) {
    __hip_bfloat16 h = __float2bfloat16(v);
    return *(ushort*)&h;
}
static __device__ __forceinline__ float ldf(const float* p, size_t i) { return p[i]; }
static __device__ __forceinline__ float ldf(const ushort* p, size_t i) {
    union { uint u; float f; } c; c.u = (uint)p[i] << 16; return c.f;
}

// ---------------------------------------------------------------- mean over H -> bf16
__global__ __launch_bounds__(256) void mean_kernel(const float* __restrict__ kv,
                                                   ushort* __restrict__ dec0b) {
    int v = blockIdx.x * blockDim.x + threadIdx.x;  // float4 index over (B,W,C)
    int total = B_ * W_ * (C_ / 4);
    if (v >= total) return;
    int c4  = v % (C_ / 4);
    int row = v / (C_ / 4);      // b*W + w
    int b = row / W_;
    int w = row % W_;
    const float4* src = (const float4*)kv + (size_t)(b * NKV + w) * (C_ / 4) + c4;
    float4 s = {0.f, 0.f, 0.f, 0.f};
#pragma unroll
    for (int h = 0; h < H_; ++h) {
        float4 t = src[(size_t)h * W_ * (C_ / 4)];
        s.x += t.x; s.y += t.y; s.z += t.z; s.w += t.w;
    }
    ushort4 o;
    o.x = f2bf(s.x * 0.125f); o.y = f2bf(s.y * 0.125f);
    o.z = f2bf(s.z * 0.125f); o.w = f2bf(s.w * 0.125f);
    ((ushort4*)dec0b)[v] = o;
}

// ---------------------------------------------------------------- cast fp32 -> bf16
__global__ __launch_bounds__(256) void cast_kernel(const float* __restrict__ in,
                                                   ushort* __restrict__ out, int n4) {
    int v = blockIdx.x * blockDim.x + threadIdx.x;
    if (v >= n4) return;
    float4 f = ((const float4*)in)[v];
    ushort4 o;
    o.x = f2bf(f.x); o.y = f2bf(f.y); o.z = f2bf(f.z); o.w = f2bf(f.w);
    ((ushort4*)out)[v] = o;
}

// ------------------------------------------------- weight transpose+cast (K,N)->(N,K)
// 32x32 LDS tiles: coalesced float4 reads of src rows, bf16 ushort4 writes of dst rows.
struct WtDesc { const float* src[12]; ushort* dst[12]; int Kd[12]; int Nd[12]; };
__global__ __launch_bounds__(256) void wtcast_kernel(WtDesc d) {
    int wi = blockIdx.y;
    int K = d.Kd[wi], N = d.Nd[wi];
    int tiles_n = N / 32;
    int tile = blockIdx.x;
    if (tile >= (K / 32) * tiles_n) return;
    int k0 = (tile / tiles_n) * 32, n0 = (tile % tiles_n) * 32;
    __shared__ float t[32][33];
    int tid = threadIdx.x;
    int r = tid >> 3, c4 = (tid & 7) * 4;
    float4 v = *(const float4*)&d.src[wi][(size_t)(k0 + r) * N + n0 + c4];
    t[r][c4] = v.x; t[r][c4 + 1] = v.y; t[r][c4 + 2] = v.z; t[r][c4 + 3] = v.w;
    __syncthreads();
    int c = tid >> 3, k4 = (tid & 7) * 4;
    ushort4 o;
    o.x = f2bf(t[k4][c]); o.y = f2bf(t[k4 + 1][c]);
    o.z = f2bf(t[k4 + 2][c]); o.w = f2bf(t[k4 + 3][c]);
    *(ushort4*)&d.dst[wi][(size_t)(n0 + c) * K + k0 + k4] = o;
}

// ---------------------------------------------------------------- bf16 MFMA GEMM 128x128
// Baseline (614us) reg-staged structure + job table: up to 3 independent GEMMs per
// dispatch, job selected by blockIdx.z (block-uniform -> barrier-safe guard).
struct GJob {
    const ushort* A; const ushort* Bt;
    const float* bias; float* Cout; ushort* Cbf;
    int M, N, K; float alpha; int act;
};
struct GJobs { GJob j[3]; };

__global__ __launch_bounds__(256) void bgemm_kernel(GJobs gs) {
    const GJob g = gs.j[blockIdx.z];
    const int bm = blockIdx.y * 128, bn = blockIdx.x * 128;
    if (bm >= g.M || bn >= g.N) return;
    __shared__ ushort As[128 * 40];
    __shared__ ushort Bs[128 * 40];
    const int tid = threadIdx.x;
    const int wav = tid >> 6, lane = tid & 63;
    const int wm = (wav >> 1) * 64, wn = (wav & 1) * 64;
    const int lrow = lane & 15, lq = lane >> 4;

    floatx4 acc[4][4] = {};

    const int sr = tid >> 1, sc0 = (tid & 1) * 16;
    const ushort* Ag = g.A + (size_t)(bm + sr) * g.K + sc0;
    const ushort* Bg = g.Bt + (size_t)(bn + sr) * g.K + sc0;
    ushort* Asw = &As[sr * 40 + sc0];
    ushort* Bsw = &Bs[sr * 40 + sc0];

    for (int k0 = 0; k0 < g.K; k0 += 32) {
        uint4 a0 = *(const uint4*)(Ag + k0);
        uint4 a1 = *(const uint4*)(Ag + k0 + 8);
        uint4 b0 = *(const uint4*)(Bg + k0);
        uint4 b1 = *(const uint4*)(Bg + k0 + 8);
        __syncthreads();
        *(uint4*)Asw = a0; *(uint4*)(Asw + 8) = a1;
        *(uint4*)Bsw = b0; *(uint4*)(Bsw + 8) = b1;
        __syncthreads();
        short8 af[4], bfr[4];
#pragma unroll
        for (int i = 0; i < 4; ++i)
            af[i] = *(const short8*)&As[(wm + 16 * i + lrow) * 40 + lq * 8];
#pragma unroll
        for (int j = 0; j < 4; ++j)
            bfr[j] = *(const short8*)&Bs[(wn + 16 * j + lrow) * 40 + lq * 8];
#pragma unroll
        for (int i = 0; i < 4; ++i)
#pragma unroll
            for (int j = 0; j < 4; ++j)
                acc[i][j] = __builtin_amdgcn_mfma_f32_16x16x32_bf16(af[i], bfr[j], acc[i][j], 0, 0, 0);
    }

#pragma unroll
    for (int i = 0; i < 4; ++i)
#pragma unroll
        for (int j = 0; j < 4; ++j) {
            int row = bm + wm + 16 * i + lq * 4;
            int col = bn + wn + 16 * j + lrow;
            float bv = g.bias ? g.bias[col] : 0.f;
#pragma unroll
            for (int r = 0; r < 4; ++r) {
                float v = acc[i][j][r] * g.alpha + bv;
                if (g.act == 1) v = tanhf(v);
                size_t off = (size_t)(row + r) * g.N + col;
                if (g.Cout) g.Cout[off] = v;
                if (g.Cbf) g.Cbf[off] = f2bf(v);
            }
        }
}

static inline void bgemmJ(hipStream_t st, int nj, const GJob* js) {
    GJobs gs;
    int mx = 0, my = 0;
    for (int i = 0; i < nj; ++i) {
        gs.j[i] = js[i];
        int nx = js[i].N / 128, ny = js[i].M / 128;
        if (nx > mx) mx = nx;
        if (ny > my) my = ny;
    }
    for (int i = nj; i < 3; ++i) gs.j[i] = js[0];
    bgemm_kernel<<<dim3(mx, my, nj), 256, 0, st>>>(gs);
}

// ------------------------------------------- generic batched 64x64 MFMA GEMM (baseline)
struct BGArgs {
    const ushort* A; const ushort* Bt;
    const float* bias; float* outF; ushort* outB;
    int lda, ldb, ldo;
    long AsB, BsB, OsB;
    int AsH, BsH, OsH;
    int K, NH;
    float alpha; int act;
};
__global__ __launch_bounds__(256) void battn_kernel(BGArgs g) {
    __shared__ ushort As[64 * 40];
    __shared__ ushort Bs[64 * 40];
    const int bn = blockIdx.x * 64, bm = blockIdx.y * 64;
    const int bat = blockIdx.z, bb = bat / g.NH, hh = bat % g.NH;
    const ushort* A  = g.A  + (size_t)bb * g.AsB + (size_t)hh * g.AsH;
    const ushort* Bt = g.Bt + (size_t)bb * g.BsB + (size_t)hh * g.BsH;
    const int tid = threadIdx.x;
    const int wav = tid >> 6, lane = tid & 63;
    const int lrow = lane & 15, lq = lane >> 4;
    const int sr = tid >> 2, sc0 = (tid & 3) * 8;
    const ushort* Ag = A  + (size_t)(bm + sr) * g.lda + sc0;
    const ushort* Bg = Bt + (size_t)(bn + sr) * g.ldb + sc0;
    ushort* Asw = &As[sr * 40 + sc0];
    ushort* Bsw = &Bs[sr * 40 + sc0];

    floatx4 acc[4] = {};

    for (int k0 = 0; k0 < g.K; k0 += 32) {
        uint4 a = *(const uint4*)(Ag + k0);
        uint4 b = *(const uint4*)(Bg + k0);
        __syncthreads();
        *(uint4*)Asw = a; *(uint4*)Bsw = b;
        __syncthreads();
        short8 af = *(const short8*)&As[(wav * 16 + lrow) * 40 + lq * 8];
#pragma unroll
        for (int j = 0; j < 4; ++j) {
            short8 bf = *(const short8*)&Bs[(16 * j + lrow) * 40 + lq * 8];
            acc[j] = __builtin_amdgcn_mfma_f32_16x16x32_bf16(af, bf, acc[j], 0, 0, 0);
        }
    }

#pragma unroll
    for (int j = 0; j < 4; ++j) {
        int col = bn + 16 * j + lrow;
        float bv = g.bias ? g.bias[col] : 0.f;
        int row0 = bm + wav * 16 + lq * 4;
#pragma unroll
        for (int r = 0; r < 4; ++r) {
            float v = acc[j][r] * g.alpha + bv;
            if (g.act == 1) v = tanhf(v);
            size_t off = (size_t)bb * g.OsB + (size_t)hh * g.OsH
                       + (size_t)(row0 + r) * g.ldo + col;
            if (g.outF) g.outF[off] = v;
            if (g.outB) g.outB[off] = f2bf(v);
        }
    }
}

static inline void battn(hipStream_t st, const ushort* A, const ushort* Bt,
                         const float* bias, float* outF, ushort* outB,
                         int M, int N, int K, float alpha, int act,
                         int lda, long AsB, int AsH,
                         int ldb, long BsB, int BsH,
                         int ldo, long OsB, int OsH,
                         int NH, int nbat) {
    BGArgs g;
    g.A = A; g.Bt = Bt; g.bias = bias; g.outF = outF; g.outB = outB;
    g.lda = lda; g.ldb = ldb; g.ldo = ldo;
    g.AsB = AsB; g.BsB = BsB; g.OsB = OsB;
    g.AsH = AsH; g.BsH = BsH; g.OsH = OsH;
    g.K = K; g.NH = NH; g.alpha = alpha; g.act = act;
    dim3 grid(N / 64, M / 64, nbat);
    battn_kernel<<<grid, 256, 0, st>>>(g);
}

static inline void bgemm64(hipStream_t st, const ushort* A, const ushort* Bt,
                           const float* bias, float* outF, ushort* outB,
                           int M, int N, int K, float alpha, int act) {
    battn(st, A, Bt, bias, outF, outB, M, N, K, alpha, act,
          K, 0, 0, K, 0, 0, N, 0, 0, 1, 1);
}

// ---------------------------------------------------------------- dual LayerNorm -> bf16
struct Ln2Desc {
    const void* X0; const float* g0; const float* b0; ushort* Y0; int bf0; int rows0;
    const void* X1; const float* g1; const float* b1; ushort* Y1; int bf1;
};
__global__ __launch_bounds__(128) void ln2_kernel(Ln2Desc d) {
    int row = blockIdx.x;
    const void* X; const float* g; const float* bb; ushort* Y; int isbf;
    if (row < d.rows0) { X = d.X0; g = d.g0; bb = d.b0; Y = d.Y0; isbf = d.bf0; }
    else { row -= d.rows0; X = d.X1; g = d.g1; bb = d.b1; Y = d.Y1; isbf = d.bf1; }
    const float*  xf = (const float*)X + (size_t)row * C_;
    const ushort* xb = (const ushort*)X + (size_t)row * C_;
    ushort* y = Y + (size_t)row * C_;
    int t = threadIdx.x;
    float v0, v1, v2;
    if (isbf) { v0 = ldf(xb, t); v1 = ldf(xb, t + 128); v2 = ldf(xb, t + 256); }
    else      { v0 = ldf(xf, t); v1 = ldf(xf, t + 128); v2 = ldf(xf, t + 256); }
    float s = v0 + v1 + v2, sq = v0 * v0 + v1 * v1 + v2 * v2;
    __shared__ float rs[128], rq[128];
    rs[t] = s; rq[t] = sq; __syncthreads();
    if (t < 64) {
        s = rs[t] + rs[t + 64]; sq = rq[t] + rq[t + 64];
        for (int o = 32; o; o >>= 1) { s += __shfl_down(s, o); sq += __shfl_down(sq, o); }
        if (t == 0) { rs[0] = s; rq[0] = sq; }
    }
    __syncthreads();
    float mean = rs[0] * (1.0f / C_);
    float var  = rq[0] * (1.0f / C_) - mean * mean;
    float inv  = rsqrtf(var + 1e-6f);
    y[t]       = f2bf((v0 - mean) * inv * g[t]       + bb[t]);
    y[t + 128] = f2bf((v1 - mean) * inv * g[t + 128] + bb[t + 128]);
    y[t + 256] = f2bf((v2 - mean) * inv * g[t + 256] + bb[t + 256]);
}

// ------------------------------------------- softmax (+ optional gauss) rows
template <int NW, int GAUSS>
__global__ __launch_bounds__(256) void softmax_kernel(
    const float* __restrict__ sc, const float* __restrict__ ptv,
    ushort* __restrict__ P)
{
    int row = blockIdx.x * 4 + (threadIdx.x >> 6);
    int lane = threadIdx.x & 63;
    const float* s = sc + (size_t)row * NW;
    float pcen = GAUSS ? ptv[row] : 0.f;
    float vals[NW / 64];
    float m = -1e30f;
#pragma unroll
    for (int i = 0; i < NW / 64; ++i) {
        int w = lane + 64 * i;
        float v = s[w];
        if (GAUSS) { float dw = (float)w - pcen; v *= expf(dw * dw * (-1.0f / 18.0f)); }
        vals[i] = v; m = fmaxf(m, v);
    }
#pragma unroll
    for (int o = 32; o; o >>= 1) m = fmaxf(m, __shfl_xor(m, o));
    float sum = 0.f;
#pragma unroll
    for (int i = 0; i < NW / 64; ++i) { vals[i] = expf(vals[i] - m); sum += vals[i]; }
#pragma unroll
    for (int o = 32; o; o >>= 1) sum += __shfl_xor(sum, o);
    float rinv = 1.0f / sum;
    ushort* op = P + (size_t)row * NW;
#pragma unroll
    for (int i = 0; i < NW / 64; ++i) op[lane + 64 * i] = f2bf(vals[i] * rinv);
}

// ------------------------------------------- v transpose: kvb (B*Nw, C2) bf16
__global__ __launch_bounds__(256) void vtrans_kernel(
    const ushort* __restrict__ kvb, ushort* __restrict__ vt,
    int Nw, int C2, int CC)
{
    int b = blockIdx.z;
    int w0 = blockIdx.x * 32, c0 = blockIdx.y * 32;
    __shared__ ushort t[32][33];
    int tid = threadIdx.x;
    int wl = tid >> 3, c4 = (tid & 7) * 4;
    ushort4 v = *(const ushort4*)&kvb[((size_t)b * Nw + w0 + wl) * C2 + CC + c0 + c4];
    t[wl][c4] = v.x; t[wl][c4 + 1] = v.y; t[wl][c4 + 2] = v.z; t[wl][c4 + 3] = v.w;
    __syncthreads();
    int dl = tid >> 3, w4 = (tid & 7) * 4;
    ushort4 o;
    o.x = t[w4][dl]; o.y = t[w4 + 1][dl]; o.z = t[w4 + 2][dl]; o.w = t[w4 + 3][dl];
    *(ushort4*)&vt[((size_t)b * CC + c0 + dl) * Nw + w0 + w4] = o;
}

// ---------------------------------------------------------------- p_t head
__global__ __launch_bounds__(128) void pt_kernel(const float* __restrict__ T,
    const float* __restrict__ vpw, const float* __restrict__ vpb,
    float* __restrict__ out) {
    int row = blockIdx.x;
    int t = threadIdx.x;
    const float* x = T + (size_t)row * C_;
    float s = x[t] * vpw[t] + x[t + 128] * vpw[t + 128] + x[t + 256] * vpw[t + 256];
    __shared__ float red[128];
    red[t] = s; __syncthreads();
    if (t < 64) {
        s = red[t] + red[t + 64];
        for (int o = 32; o; o >>= 1) s += __shfl_down(s, o);
        if (t == 0) {
            float z = s + vpb[0];
            out[row] = 512.0f / (1.0f + expf(-z));
        }
    }
}

// ---------------------------------------------------------------- launch
extern "C" void kernel_launch(void* const* d_in, const int* in_sizes, int n_in,
                              void* d_out, int out_size, void* d_ws, size_t ws_size,
                              hipStream_t stream) {
    const float* q     = (const float*)d_in[0];
    const float* kv    = (const float*)d_in[1];
    const float* Wq    = (const float*)d_in[2];
    const float* Wkv   = (const float*)d_in[3];
    const float* Wproj = (const float*)d_in[4];
    const float* bproj = (const float*)d_in[5];
    const float* Wp_w  = (const float*)d_in[6];
    const float* Wp_b  = (const float*)d_in[7];
    const float* vp_w  = (const float*)d_in[8];
    const float* vp_b  = (const float*)d_in[9];
    const float* Wqpos = (const float*)d_in[10];
    const float* bqpos = (const float*)d_in[11];
    const float* Wrctc = (const float*)d_in[12];
    const float* brctc = (const float*)d_in[13];
    const float* ca1_Wq    = (const float*)d_in[14];
    const float* ca1_Wkv   = (const float*)d_in[15];
    const float* ca1_Wproj = (const float*)d_in[16];
    const float* ca1_bproj = (const float*)d_in[17];
    const float* ca2_Wq    = (const float*)d_in[18];
    const float* ca2_Wkv   = (const float*)d_in[19];
    const float* ca2_Wproj = (const float*)d_in[20];
    const float* ca2_bproj = (const float*)d_in[21];
    const float* g_q1  = (const float*)d_in[22];
    const float* b_q1  = (const float*)d_in[23];
    const float* g_kv1 = (const float*)d_in[24];
    const float* b_kv1 = (const float*)d_in[25];
    const float* g_q2  = (const float*)d_in[26];
    const float* b_q2  = (const float*)d_in[27];
    const float* g_kv2 = (const float*)d_in[28];
    const float* b_kv2 = (const float*)d_in[29];
    float* out = (float*)d_out;
    float* ws  = (float*)d_ws;

    // workspace layout (float offsets), total 34140160 fl ~ 136.6 MB
    ushort* dec0b = (ushort*)(ws);                   // 6291456 ush
    ushort* wb    = (ushort*)(ws + 3145728);         // 2211840 ush
    ushort* qb    = (ushort*)(ws + 4251648);         // 1572864 ush
    ushort* decb  = (ushort*)(ws + 5038080);         // 6291456 ush
    ushort* qhb   = (ushort*)(ws + 8183808);         // 1572864 ush
    float*  p     = ws + 8970240;                    // 1572864 fl
    ushort* pb    = (ushort*)(ws + 10543104);        // 1572864 ush
    float*  t1    = ws + 11329536;                   // 1572864 fl
    ushort* t1b   = (ushort*)(ws + 12902400);        // 1572864 ush
    ushort* t2b   = (ushort*)(ws + 13688832);        // 6291456 ush
    ushort* qpb   = (ushort*)(ws + 16834560);        // 1572864 ush
    ushort* kvb   = (ushort*)(ws + 17620992);        // 12582912 ush
    ushort* vt    = (ushort*)(ws + 23912448);        // 6291456 ush
    float*  sc    = ws + 27058176;                   // 4194304 fl
    ushort* Pb    = (ushort*)(ws + 31252480);        // 4194304 ush
    ushort* xb    = (ushort*)(ws + 33349632);        // 1572864 ush
    float*  ptb   = ws + 34136064;                   // 4096 fl

    // bf16 transposed weight sub-offsets (ushort units)
    ushort* wbWq     = wb;
    ushort* wbWqpos  = wb + 147456;
    ushort* wbWrctc  = wb + 294912;
    ushort* wbC1Wq   = wb + 442368;
    ushort* wbC1Wp   = wb + 589824;
    ushort* wbC2Wq   = wb + 737280;
    ushort* wbC2Wp   = wb + 884736;
    ushort* wbWpw    = wb + 1032192;
    ushort* wbWproj  = wb + 1179648;
    ushort* wbWkv    = wb + 1327104;
    ushort* wbC1Wkv  = wb + 1622016;
    ushort* wbC2Wkv  = wb + 1916928;

    const float rs384 = 0.05103103630798288f;  // 1/sqrt(384)
    const float rs192 = 0.07216878364870323f;  // 1/sqrt(192)

    // 1. mean over H -> bf16
    mean_kernel<<<(B_ * W_ * (C_ / 4) + 255) / 256, 256, 0, stream>>>(kv, dec0b);
    // 2. weight transpose-casts + q cast
    {
        WtDesc d;
        const float* s_[12] = {Wq, Wqpos, Wrctc, ca1_Wq, ca1_Wproj, ca2_Wq, ca2_Wproj,
                               Wp_w, Wproj, Wkv, ca1_Wkv, ca2_Wkv};
        ushort* t_[12] = {wbWq, wbWqpos, wbWrctc, wbC1Wq, wbC1Wp, wbC2Wq, wbC2Wp,
                          wbWpw, wbWproj, wbWkv, wbC1Wkv, wbC2Wkv};
        for (int i = 0; i < 12; ++i) {
            d.src[i] = s_[i]; d.dst[i] = t_[i];
            d.Kd[i] = 384; d.Nd[i] = (i >= 9) ? 768 : 384;
        }
        dim3 grid(288, 12);
        wtcast_kernel<<<grid, 256, 0, stream>>>(d);
        cast_kernel<<<(393216 + 255) / 256, 256, 0, stream>>>(q, qb, 393216);
    }
    // 3+4. J1: {dec = dec0@Wrctc, qh = (q@Wq)*rs384, p = q@Wqpos + bqpos}
    {
        GJob js[3];
        js[0] = {dec0b, wbWrctc, brctc, nullptr, decb, B_ * W_, 384, 384, 1.f, 0};
        js[1] = {qb, wbWq, nullptr, nullptr, qhb, B_ * S_, 384, 384, rs384, 0};
        js[2] = {qb, wbWqpos, bqpos, p, nullptr, B_ * S_, 384, 384, 1.f, 0};
        bgemmJ(stream, 3, js);
    }
    // 5. ca1
    {
        Ln2Desc d;
        d.X0 = p; d.g0 = g_q1;  d.b0 = b_q1;  d.Y0 = t1b; d.bf0 = 0; d.rows0 = B_ * S_;
        d.X1 = q; d.g1 = g_kv1; d.b1 = b_kv1; d.Y1 = t2b; d.bf1 = 0;
        ln2_kernel<<<2 * B_ * S_, 128, 0, stream>>>(d);
    }
    {
        GJob js[2];
        js[0] = {t1b, wbC1Wq, nullptr, nullptr, qpb, B_ * S_, 384, 384, rs192, 0};
        js[1] = {t2b, wbC1Wkv, nullptr, nullptr, kvb, B_ * S_, 768, 384, 1.f, 0};
        bgemmJ(stream, 2, js);
    }
    {
        dim3 gt(S_ / 32, C_ / 32, B_);
        vtrans_kernel<<<gt, 256, 0, stream>>>(kvb, vt, S_, 768, 384);
    }
    battn(stream, qpb, kvb, nullptr, sc, nullptr, 128, 128, 192, 1.f, 0,
          384, (long)S_ * 384, 192,
          768, (long)S_ * 768, 192,
          128, (long)2 * S_ * 128, S_ * 128, 2, 64);
    softmax_kernel<128, 0><<<(B_ * 2 * S_) / 4, 256, 0, stream>>>(sc, nullptr, Pb);
    battn(stream, Pb, vt, nullptr, nullptr, xb, 128, 192, 128, 1.f, 0,
          128, (long)2 * S_ * 128, S_ * 128,
          128, (long)C_ * S_, 192 * S_,
          384, (long)S_ * 384, 192, 2, 64);
    bgemm64(stream, xb, wbC1Wp, ca1_bproj, p, nullptr, B_ * S_, 384, 384, 1.f, 0);
    // 6. ca2
    {
        Ln2Desc d;
        d.X0 = p;    d.g0 = g_q2;  d.b0 = b_q2;  d.Y0 = t1b; d.bf0 = 0; d.rows0 = B_ * S_;
        d.X1 = decb; d.g1 = g_kv2; d.b1 = b_kv2; d.Y1 = t2b; d.bf1 = 1;
        ln2_kernel<<<B_ * S_ + B_ * W_, 128, 0, stream>>>(d);
    }
    {
        GJob js[2];
        js[0] = {t1b, wbC2Wq, nullptr, nullptr, qpb, B_ * S_, 384, 384, rs192, 0};
        js[1] = {t2b, wbC2Wkv, nullptr, nullptr, kvb, B_ * W_, 768, 384, 1.f, 0};
        bgemmJ(stream, 2, js);
    }
    {
        dim3 gt(W_ / 32, C_ / 32, B_);
        vtrans_kernel<<<gt, 256, 0, stream>>>(kvb, vt, W_, 768, 384);
    }
    battn(stream, qpb, kvb, nullptr, sc, nullptr, 128, 512, 192, 1.f, 0,
          384, (long)S_ * 384, 192,
          768, (long)W_ * 768, 192,
          512, (long)2 * S_ * 512, S_ * 512, 2, 64);
    softmax_kernel<512, 0><<<(B_ * 2 * S_) / 4, 256, 0, stream>>>(sc, nullptr, Pb);
    battn(stream, Pb, vt, nullptr, nullptr, xb, 128, 192, 512, 1.f, 0,
          512, (long)2 * S_ * 512, S_ * 512,
          512, (long)C_ * W_, 192 * W_,
          384, (long)S_ * 384, 192, 2, 64);
    bgemm64(stream, xb, wbC2Wp, ca2_bproj, p, pb, B_ * S_, 384, 384, 1.f, 0);
    // 7+8. J4: {p_t tanh GEMM, main k/v = dec @ Wkv}
    {
        GJob js[2];
        js[0] = {pb, wbWpw, Wp_b, t1, nullptr, B_ * S_, 384, 384, 1.f, 1};
        js[1] = {decb, wbWkv, nullptr, nullptr, kvb, B_ * W_, 768, 384, 1.f, 0};
        bgemmJ(stream, 2, js);
    }
    pt_kernel<<<B_ * S_, 128, 0, stream>>>(t1, vp_w, vp_b, ptb);
    {
        dim3 gt(W_ / 32, C_ / 32, B_);
        vtrans_kernel<<<gt, 256, 0, stream>>>(kvb, vt, W_, 768, 384);
    }
    // 9. main attention: scores, gauss-softmax, PV
    battn(stream, qhb, kvb, nullptr, sc, nullptr, 128, 512, 384, 1.f, 0,
          384, (long)S_ * 384, 0,
          768, (long)W_ * 768, 0,
          512, (long)S_ * 512, 0, 1, 32);
    softmax_kernel<512, 1><<<(B_ * S_) / 4, 256, 0, stream>>>(sc, ptb, Pb);
    battn(stream, Pb, vt, nullptr, nullptr, xb, 128, 384, 512, 1.f, 0,
          512, (long)S_ * 512, 0,
          512, (long)C_ * W_, 0,
          384, (long)S_ * 384, 0, 1, 32);
    // 10. out = x @ Wproj + bproj (fp32)
    bgemm64(stream, xb, wbWproj, bproj, out, nullptr, B_ * S_, 384, 384, 1.f, 0);
}

// Round 4
// 562.422 us; speedup vs baseline: 1.1794x; 1.0432x over previous
//
#include <hip/hip_runtime.h>
#include <hip/hip_bf16.h>
#include <math.h>

#define B_ 32
#define S_ 128
#define C_ 384
#define H_ 8
#define W_ 512
#define NKV 4096   // H_*W_

typedef __attribute__((ext_vector_type(8))) short short8;
typedef __attribute__((ext_vector_type(4))) float floatx4;

static __device__ __forceinline__ ushort f2bf(float v) {
    __hip_bfloat16 h = __float2bfloat16(v);
    return *(ushort*)&h;
}
static __device__ __forceinline__ float ldf(const float* p, size_t i) { return p[i]; }
static __device__ __forceinline__ float ldf(const ushort* p, size_t i) {
    union { uint u; float f; } c; c.u = (uint)p[i] << 16; return c.f;
}

// ------------------------------------------- prep: mean over H -> bf16, q cast -> bf16
__global__ __launch_bounds__(256) void prep_kernel(const float* __restrict__ kv,
                                                   ushort* __restrict__ dec0b,
                                                   const float* __restrict__ q,
                                                   ushort* __restrict__ qb) {
    int v = blockIdx.x * 256 + threadIdx.x;
    const int meanTot = B_ * W_ * (C_ / 4);     // 1572864... (float4 over B,W,C)
    if (v < meanTot) {
        int c4  = v % (C_ / 4);
        int row = v / (C_ / 4);      // b*W + w
        int b = row / W_;
        int w = row % W_;
        const float4* src = (const float4*)kv + (size_t)(b * NKV + w) * (C_ / 4) + c4;
        float4 s = {0.f, 0.f, 0.f, 0.f};
#pragma unroll
        for (int h = 0; h < H_; ++h) {
            float4 t = src[(size_t)h * W_ * (C_ / 4)];
            s.x += t.x; s.y += t.y; s.z += t.z; s.w += t.w;
        }
        ushort4 o;
        o.x = f2bf(s.x * 0.125f); o.y = f2bf(s.y * 0.125f);
        o.z = f2bf(s.z * 0.125f); o.w = f2bf(s.w * 0.125f);
        ((ushort4*)dec0b)[v] = o;
        return;
    }
    v -= meanTot;
    const int castTot = B_ * S_ * (C_ / 4);     // 393216
    if (v >= castTot) return;
    float4 f = ((const float4*)q)[v];
    ushort4 o;
    o.x = f2bf(f.x); o.y = f2bf(f.y); o.z = f2bf(f.z); o.w = f2bf(f.w);
    ((ushort4*)qb)[v] = o;
}

// ------------------------------------------------- weight transpose+cast (K,N)->(N,K)
// 32x32 LDS tiles: coalesced float4 reads of src rows, bf16 ushort4 writes of dst rows.
struct WtDesc { const float* src[12]; ushort* dst[12]; int Kd[12]; int Nd[12]; };
__global__ __launch_bounds__(256) void wtcast_kernel(WtDesc d) {
    int wi = blockIdx.y;
    int K = d.Kd[wi], N = d.Nd[wi];
    int tiles_n = N / 32;
    int tile = blockIdx.x;
    if (tile >= (K / 32) * tiles_n) return;
    int k0 = (tile / tiles_n) * 32, n0 = (tile % tiles_n) * 32;
    __shared__ float t[32][33];
    int tid = threadIdx.x;
    int r = tid >> 3, c4 = (tid & 7) * 4;
    float4 v = *(const float4*)&d.src[wi][(size_t)(k0 + r) * N + n0 + c4];
    t[r][c4] = v.x; t[r][c4 + 1] = v.y; t[r][c4 + 2] = v.z; t[r][c4 + 3] = v.w;
    __syncthreads();
    int c = tid >> 3, k4 = (tid & 7) * 4;
    ushort4 o;
    o.x = f2bf(t[k4][c]); o.y = f2bf(t[k4 + 1][c]);
    o.z = f2bf(t[k4 + 2][c]); o.w = f2bf(t[k4 + 3][c]);
    *(ushort4*)&d.dst[wi][(size_t)(n0 + c) * K + k0 + k4] = o;
}

// ---------------------------------------------------------------- bf16 MFMA GEMM 128x128
// Reg-staged 128x128 + job table (up to 3 GEMMs / dispatch) + K-loop software pipeline:
// next step's global loads issued before current step's ds_read+MFMA.
struct GJob {
    const ushort* A; const ushort* Bt;
    const float* bias; float* Cout; ushort* Cbf;
    int M, N, K; float alpha; int act;
};
struct GJobs { GJob j[3]; };

__global__ __launch_bounds__(256) void bgemm_kernel(GJobs gs) {
    const GJob g = gs.j[blockIdx.z];
    const int bm = blockIdx.y * 128, bn = blockIdx.x * 128;
    if (bm >= g.M || bn >= g.N) return;
    __shared__ ushort As[128 * 40];
    __shared__ ushort Bs[128 * 40];
    const int tid = threadIdx.x;
    const int wav = tid >> 6, lane = tid & 63;
    const int wm = (wav >> 1) * 64, wn = (wav & 1) * 64;
    const int lrow = lane & 15, lq = lane >> 4;

    floatx4 acc[4][4] = {};

    const int sr = tid >> 1, sc0 = (tid & 1) * 16;
    const ushort* Ag = g.A + (size_t)(bm + sr) * g.K + sc0;
    const ushort* Bg = g.Bt + (size_t)(bn + sr) * g.K + sc0;
    ushort* Asw = &As[sr * 40 + sc0];
    ushort* Bsw = &Bs[sr * 40 + sc0];

    uint4 a0 = *(const uint4*)(Ag);
    uint4 a1 = *(const uint4*)(Ag + 8);
    uint4 b0 = *(const uint4*)(Bg);
    uint4 b1 = *(const uint4*)(Bg + 8);

    for (int k0 = 0; k0 < g.K; k0 += 32) {
        __syncthreads();
        *(uint4*)Asw = a0; *(uint4*)(Asw + 8) = a1;
        *(uint4*)Bsw = b0; *(uint4*)(Bsw + 8) = b1;
        __syncthreads();
        if (k0 + 32 < g.K) {          // prefetch next step; overlaps MFMA below
            a0 = *(const uint4*)(Ag + k0 + 32);
            a1 = *(const uint4*)(Ag + k0 + 40);
            b0 = *(const uint4*)(Bg + k0 + 32);
            b1 = *(const uint4*)(Bg + k0 + 40);
        }
        short8 af[4], bfr[4];
#pragma unroll
        for (int i = 0; i < 4; ++i)
            af[i] = *(const short8*)&As[(wm + 16 * i + lrow) * 40 + lq * 8];
#pragma unroll
        for (int j = 0; j < 4; ++j)
            bfr[j] = *(const short8*)&Bs[(wn + 16 * j + lrow) * 40 + lq * 8];
#pragma unroll
        for (int i = 0; i < 4; ++i)
#pragma unroll
            for (int j = 0; j < 4; ++j)
                acc[i][j] = __builtin_amdgcn_mfma_f32_16x16x32_bf16(af[i], bfr[j], acc[i][j], 0, 0, 0);
    }

#pragma unroll
    for (int i = 0; i < 4; ++i)
#pragma unroll
        for (int j = 0; j < 4; ++j) {
            int row = bm + wm + 16 * i + lq * 4;
            int col = bn + wn + 16 * j + lrow;
            float bv = g.bias ? g.bias[col] : 0.f;
#pragma unroll
            for (int r = 0; r < 4; ++r) {
                float v = acc[i][j][r] * g.alpha + bv;
                if (g.act == 1) v = tanhf(v);
                size_t off = (size_t)(row + r) * g.N + col;
                if (g.Cout) g.Cout[off] = v;
                if (g.Cbf) g.Cbf[off] = f2bf(v);
            }
        }
}

static inline void bgemmJ(hipStream_t st, int nj, const GJob* js) {
    GJobs gs;
    int mx = 0, my = 0;
    for (int i = 0; i < nj; ++i) {
        gs.j[i] = js[i];
        int nx = js[i].N / 128, ny = js[i].M / 128;
        if (nx > mx) mx = nx;
        if (ny > my) my = ny;
    }
    for (int i = nj; i < 3; ++i) gs.j[i] = js[0];
    bgemm_kernel<<<dim3(mx, my, nj), 256, 0, st>>>(gs);
}

// ------------------------------------------- generic batched 64x64 MFMA GEMM
// + K-loop software pipeline + optional fused 32x32 v-transpose blocks packed into
// extra blockIdx.z slices (flat-indexed, zero waste).
struct BGArgs {
    const ushort* A; const ushort* Bt;
    const float* bias; float* outF; ushort* outB;
    int lda, ldb, ldo;
    long AsB, BsB, OsB;
    int AsH, BsH, OsH;
    int K, NH;
    float alpha; int act;
    int nbat;
    const ushort* vtsrc; ushort* vtdst; int vtNw;
};
__global__ __launch_bounds__(256) void battn_kernel(BGArgs g) {
    __shared__ ushort As[64 * 40];
    __shared__ ushort Bs[64 * 40];
    const int tid = threadIdx.x;
    const int bat = blockIdx.z;
    if (bat >= g.nbat) {
        // -------- fused v-transpose tile: kvb (B*Nw,768) v-part -> vt (B,384,Nw)
        int flat = (bat - g.nbat) * (gridDim.x * gridDim.y)
                 + blockIdx.y * gridDim.x + blockIdx.x;
        int wt_n = g.vtNw >> 5;
        int tiles = wt_n * (C_ / 32);
        if (flat >= B_ * tiles) return;
        int b  = flat / tiles, rr = flat % tiles;
        int w0 = (rr % wt_n) * 32, c0 = (rr / wt_n) * 32;
        ushort (*t)[33] = (ushort (*)[33])As;
        int wl = tid >> 3, c4 = (tid & 7) * 4;
        ushort4 v = *(const ushort4*)&g.vtsrc[((size_t)b * g.vtNw + w0 + wl) * 768 + 384 + c0 + c4];
        t[wl][c4] = v.x; t[wl][c4 + 1] = v.y; t[wl][c4 + 2] = v.z; t[wl][c4 + 3] = v.w;
        __syncthreads();
        int dl = tid >> 3, w4 = (tid & 7) * 4;
        ushort4 o;
        o.x = t[w4][dl]; o.y = t[w4 + 1][dl]; o.z = t[w4 + 2][dl]; o.w = t[w4 + 3][dl];
        *(ushort4*)&g.vtdst[((size_t)b * C_ + c0 + dl) * g.vtNw + w0 + w4] = o;
        return;
    }
    const int bn = blockIdx.x * 64, bm = blockIdx.y * 64;
    const int bb = bat / g.NH, hh = bat % g.NH;
    const ushort* A  = g.A  + (size_t)bb * g.AsB + (size_t)hh * g.AsH;
    const ushort* Bt = g.Bt + (size_t)bb * g.BsB + (size_t)hh * g.BsH;
    const int wav = tid >> 6, lane = tid & 63;
    const int lrow = lane & 15, lq = lane >> 4;
    const int sr = tid >> 2, sc0 = (tid & 3) * 8;
    const ushort* Ag = A  + (size_t)(bm + sr) * g.lda + sc0;
    const ushort* Bg = Bt + (size_t)(bn + sr) * g.ldb + sc0;
    ushort* Asw = &As[sr * 40 + sc0];
    ushort* Bsw = &Bs[sr * 40 + sc0];

    floatx4 acc[4] = {};

    uint4 a = *(const uint4*)(Ag);
    uint4 b = *(const uint4*)(Bg);

    for (int k0 = 0; k0 < g.K; k0 += 32) {
        __syncthreads();
        *(uint4*)Asw = a; *(uint4*)Bsw = b;
        __syncthreads();
        if (k0 + 32 < g.K) {          // prefetch next step; overlaps MFMA below
            a = *(const uint4*)(Ag + k0 + 32);
            b = *(const uint4*)(Bg + k0 + 32);
        }
        short8 af = *(const short8*)&As[(wav * 16 + lrow) * 40 + lq * 8];
#pragma unroll
        for (int j = 0; j < 4; ++j) {
            short8 bf = *(const short8*)&Bs[(16 * j + lrow) * 40 + lq * 8];
            acc[j] = __builtin_amdgcn_mfma_f32_16x16x32_bf16(af, bf, acc[j], 0, 0, 0);
        }
    }

#pragma unroll
    for (int j = 0; j < 4; ++j) {
        int col = bn + 16 * j + lrow;
        float bv = g.bias ? g.bias[col] : 0.f;
        int row0 = bm + wav * 16 + lq * 4;
#pragma unroll
        for (int r = 0; r < 4; ++r) {
            float v = acc[j][r] * g.alpha + bv;
            if (g.act == 1) v = tanhf(v);
            size_t off = (size_t)bb * g.OsB + (size_t)hh * g.OsH
                       + (size_t)(row0 + r) * g.ldo + col;
            if (g.outF) g.outF[off] = v;
            if (g.outB) g.outB[off] = f2bf(v);
        }
    }
}

static inline void battn(hipStream_t st, const ushort* A, const ushort* Bt,
                         const float* bias, float* outF, ushort* outB,
                         int M, int N, int K, float alpha, int act,
                         int lda, long AsB, int AsH,
                         int ldb, long BsB, int BsH,
                         int ldo, long OsB, int OsH,
                         int NH, int nbat,
                         const ushort* vtsrc = nullptr, ushort* vtdst = nullptr,
                         int vtNw = 0) {
    BGArgs g;
    g.A = A; g.Bt = Bt; g.bias = bias; g.outF = outF; g.outB = outB;
    g.lda = lda; g.ldb = ldb; g.ldo = ldo;
    g.AsB = AsB; g.BsB = BsB; g.OsB = OsB;
    g.AsH = AsH; g.BsH = BsH; g.OsH = OsH;
    g.K = K; g.NH = NH; g.alpha = alpha; g.act = act;
    g.nbat = nbat; g.vtsrc = vtsrc; g.vtdst = vtdst; g.vtNw = vtNw;
    int gx = N / 64, gy = M / 64, gz = nbat;
    if (vtsrc) {
        int nvt = B_ * (vtNw / 32) * (C_ / 32);
        int per = gx * gy;
        gz += (nvt + per - 1) / per;
    }
    battn_kernel<<<dim3(gx, gy, gz), 256, 0, st>>>(g);
}

static inline void bgemm64(hipStream_t st, const ushort* A, const ushort* Bt,
                           const float* bias, float* outF, ushort* outB,
                           int M, int N, int K, float alpha, int act) {
    battn(st, A, Bt, bias, outF, outB, M, N, K, alpha, act,
          K, 0, 0, K, 0, 0, N, 0, 0, 1, 1);
}

// ---------------------------------------------------------------- dual LayerNorm -> bf16
struct Ln2Desc {
    const void* X0; const float* g0; const float* b0; ushort* Y0; int bf0; int rows0;
    const void* X1; const float* g1; const float* b1; ushort* Y1; int bf1;
};
__global__ __launch_bounds__(128) void ln2_kernel(Ln2Desc d) {
    int row = blockIdx.x;
    const void* X; const float* g; const float* bb; ushort* Y; int isbf;
    if (row < d.rows0) { X = d.X0; g = d.g0; bb = d.b0; Y = d.Y0; isbf = d.bf0; }
    else { row -= d.rows0; X = d.X1; g = d.g1; bb = d.b1; Y = d.Y1; isbf = d.bf1; }
    const float*  xf = (const float*)X + (size_t)row * C_;
    const ushort* xb = (const ushort*)X + (size_t)row * C_;
    ushort* y = Y + (size_t)row * C_;
    int t = threadIdx.x;
    float v0, v1, v2;
    if (isbf) { v0 = ldf(xb, t); v1 = ldf(xb, t + 128); v2 = ldf(xb, t + 256); }
    else      { v0 = ldf(xf, t); v1 = ldf(xf, t + 128); v2 = ldf(xf, t + 256); }
    float s = v0 + v1 + v2, sq = v0 * v0 + v1 * v1 + v2 * v2;
    __shared__ float rs[128], rq[128];
    rs[t] = s; rq[t] = sq; __syncthreads();
    if (t < 64) {
        s = rs[t] + rs[t + 64]; sq = rq[t] + rq[t + 64];
        for (int o = 32; o; o >>= 1) { s += __shfl_down(s, o); sq += __shfl_down(sq, o); }
        if (t == 0) { rs[0] = s; rq[0] = sq; }
    }
    __syncthreads();
    float mean = rs[0] * (1.0f / C_);
    float var  = rq[0] * (1.0f / C_) - mean * mean;
    float inv  = rsqrtf(var + 1e-6f);
    y[t]       = f2bf((v0 - mean) * inv * g[t]       + bb[t]);
    y[t + 128] = f2bf((v1 - mean) * inv * g[t + 128] + bb[t + 128]);
    y[t + 256] = f2bf((v2 - mean) * inv * g[t + 256] + bb[t + 256]);
}

// ------------------------------------------- softmax (+ optional gauss) rows
template <int NW, int GAUSS>
__global__ __launch_bounds__(256) void softmax_kernel(
    const float* __restrict__ sc, const float* __restrict__ ptv,
    ushort* __restrict__ P)
{
    int row = blockIdx.x * 4 + (threadIdx.x >> 6);
    int lane = threadIdx.x & 63;
    const float* s = sc + (size_t)row * NW;
    float pcen = GAUSS ? ptv[row] : 0.f;
    float vals[NW / 64];
    float m = -1e30f;
#pragma unroll
    for (int i = 0; i < NW / 64; ++i) {
        int w = lane + 64 * i;
        float v = s[w];
        if (GAUSS) { float dw = (float)w - pcen; v *= expf(dw * dw * (-1.0f / 18.0f)); }
        vals[i] = v; m = fmaxf(m, v);
    }
#pragma unroll
    for (int o = 32; o; o >>= 1) m = fmaxf(m, __shfl_xor(m, o));
    float sum = 0.f;
#pragma unroll
    for (int i = 0; i < NW / 64; ++i) { vals[i] = expf(vals[i] - m); sum += vals[i]; }
#pragma unroll
    for (int o = 32; o; o >>= 1) sum += __shfl_xor(sum, o);
    float rinv = 1.0f / sum;
    ushort* op = P + (size_t)row * NW;
#pragma unroll
    for (int i = 0; i < NW / 64; ++i) op[lane + 64 * i] = f2bf(vals[i] * rinv);
}

// ---------------------------------------------------------------- p_t head
__global__ __launch_bounds__(128) void pt_kernel(const float* __restrict__ T,
    const float* __restrict__ vpw, const float* __restrict__ vpb,
    float* __restrict__ out) {
    int row = blockIdx.x;
    int t = threadIdx.x;
    const float* x = T + (size_t)row * C_;
    float s = x[t] * vpw[t] + x[t + 128] * vpw[t + 128] + x[t + 256] * vpw[t + 256];
    __shared__ float red[128];
    red[t] = s; __syncthreads();
    if (t < 64) {
        s = red[t] + red[t + 64];
        for (int o = 32; o; o >>= 1) s += __shfl_down(s, o);
        if (t == 0) {
            float z = s + vpb[0];
            out[row] = 512.0f / (1.0f + expf(-z));
        }
    }
}

// ---------------------------------------------------------------- launch
extern "C" void kernel_launch(void* const* d_in, const int* in_sizes, int n_in,
                              void* d_out, int out_size, void* d_ws, size_t ws_size,
                              hipStream_t stream) {
    const float* q     = (const float*)d_in[0];
    const float* kv    = (const float*)d_in[1];
    const float* Wq    = (const float*)d_in[2];
    const float* Wkv   = (const float*)d_in[3];
    const float* Wproj = (const float*)d_in[4];
    const float* bproj = (const float*)d_in[5];
    const float* Wp_w  = (const float*)d_in[6];
    const float* Wp_b  = (const float*)d_in[7];
    const float* vp_w  = (const float*)d_in[8];
    const float* vp_b  = (const float*)d_in[9];
    const float* Wqpos = (const float*)d_in[10];
    const float* bqpos = (const float*)d_in[11];
    const float* Wrctc = (const float*)d_in[12];
    const float* brctc = (const float*)d_in[13];
    const float* ca1_Wq    = (const float*)d_in[14];
    const float* ca1_Wkv   = (const float*)d_in[15];
    const float* ca1_Wproj = (const float*)d_in[16];
    const float* ca1_bproj = (const float*)d_in[17];
    const float* ca2_Wq    = (const float*)d_in[18];
    const float* ca2_Wkv   = (const float*)d_in[19];
    const float* ca2_Wproj = (const float*)d_in[20];
    const float* ca2_bproj = (const float*)d_in[21];
    const float* g_q1  = (const float*)d_in[22];
    const float* b_q1  = (const float*)d_in[23];
    const float* g_kv1 = (const float*)d_in[24];
    const float* b_kv1 = (const float*)d_in[25];
    const float* g_q2  = (const float*)d_in[26];
    const float* b_q2  = (const float*)d_in[27];
    const float* g_kv2 = (const float*)d_in[28];
    const float* b_kv2 = (const float*)d_in[29];
    float* out = (float*)d_out;
    float* ws  = (float*)d_ws;

    // workspace layout (float offsets), total 34140160 fl ~ 136.6 MB
    ushort* dec0b = (ushort*)(ws);                   // 6291456 ush
    ushort* wb    = (ushort*)(ws + 3145728);         // 2211840 ush
    ushort* qb    = (ushort*)(ws + 4251648);         // 1572864 ush
    ushort* decb  = (ushort*)(ws + 5038080);         // 6291456 ush
    ushort* qhb   = (ushort*)(ws + 8183808);         // 1572864 ush
    float*  p     = ws + 8970240;                    // 1572864 fl
    ushort* pb    = (ushort*)(ws + 10543104);        // 1572864 ush
    float*  t1    = ws + 11329536;                   // 1572864 fl
    ushort* t1b   = (ushort*)(ws + 12902400);        // 1572864 ush
    ushort* t2b   = (ushort*)(ws + 13688832);        // 6291456 ush
    ushort* qpb   = (ushort*)(ws + 16834560);        // 1572864 ush
    ushort* kvb   = (ushort*)(ws + 17620992);        // 12582912 ush
    ushort* vt    = (ushort*)(ws + 23912448);        // 6291456 ush
    float*  sc    = ws + 27058176;                   // 4194304 fl
    ushort* Pb    = (ushort*)(ws + 31252480);        // 4194304 ush
    ushort* xb    = (ushort*)(ws + 33349632);        // 1572864 ush
    float*  ptb   = ws + 34136064;                   // 4096 fl

    // bf16 transposed weight sub-offsets (ushort units)
    ushort* wbWq     = wb;
    ushort* wbWqpos  = wb + 147456;
    ushort* wbWrctc  = wb + 294912;
    ushort* wbC1Wq   = wb + 442368;
    ushort* wbC1Wp   = wb + 589824;
    ushort* wbC2Wq   = wb + 737280;
    ushort* wbC2Wp   = wb + 884736;
    ushort* wbWpw    = wb + 1032192;
    ushort* wbWproj  = wb + 1179648;
    ushort* wbWkv    = wb + 1327104;
    ushort* wbC1Wkv  = wb + 1622016;
    ushort* wbC2Wkv  = wb + 1916928;

    const float rs384 = 0.05103103630798288f;  // 1/sqrt(384)
    const float rs192 = 0.07216878364870323f;  // 1/sqrt(192)

    // 1. prep: mean over H -> bf16, q cast -> bf16
    prep_kernel<<<(B_ * W_ * (C_ / 4) + B_ * S_ * (C_ / 4) + 255) / 256, 256, 0, stream>>>(
        kv, dec0b, q, qb);
    // 2. weight transpose-casts
    {
        WtDesc d;
        const float* s_[12] = {Wq, Wqpos, Wrctc, ca1_Wq, ca1_Wproj, ca2_Wq, ca2_Wproj,
                               Wp_w, Wproj, Wkv, ca1_Wkv, ca2_Wkv};
        ushort* t_[12] = {wbWq, wbWqpos, wbWrctc, wbC1Wq, wbC1Wp, wbC2Wq, wbC2Wp,
                          wbWpw, wbWproj, wbWkv, wbC1Wkv, wbC2Wkv};
        for (int i = 0; i < 12; ++i) {
            d.src[i] = s_[i]; d.dst[i] = t_[i];
            d.Kd[i] = 384; d.Nd[i] = (i >= 9) ? 768 : 384;
        }
        dim3 grid(288, 12);
        wtcast_kernel<<<grid, 256, 0, stream>>>(d);
    }
    // 3+4. J1: {dec = dec0@Wrctc, qh = (q@Wq)*rs384, p = q@Wqpos + bqpos}
    {
        GJob js[3];
        js[0] = {dec0b, wbWrctc, brctc, nullptr, decb, B_ * W_, 384, 384, 1.f, 0};
        js[1] = {qb, wbWq, nullptr, nullptr, qhb, B_ * S_, 384, 384, rs384, 0};
        js[2] = {qb, wbWqpos, bqpos, p, nullptr, B_ * S_, 384, 384, 1.f, 0};
        bgemmJ(stream, 3, js);
    }
    // 5. ca1
    {
        Ln2Desc d;
        d.X0 = p; d.g0 = g_q1;  d.b0 = b_q1;  d.Y0 = t1b; d.bf0 = 0; d.rows0 = B_ * S_;
        d.X1 = q; d.g1 = g_kv1; d.b1 = b_kv1; d.Y1 = t2b; d.bf1 = 0;
        ln2_kernel<<<2 * B_ * S_, 128, 0, stream>>>(d);
    }
    {
        GJob js[2];
        js[0] = {t1b, wbC1Wq, nullptr, nullptr, qpb, B_ * S_, 384, 384, rs192, 0};
        js[1] = {t2b, wbC1Wkv, nullptr, nullptr, kvb, B_ * S_, 768, 384, 1.f, 0};
        bgemmJ(stream, 2, js);
    }
    battn(stream, qpb, kvb, nullptr, sc, nullptr, 128, 128, 192, 1.f, 0,
          384, (long)S_ * 384, 192,
          768, (long)S_ * 768, 192,
          128, (long)2 * S_ * 128, S_ * 128, 2, 64,
          kvb, vt, S_);
    softmax_kernel<128, 0><<<(B_ * 2 * S_) / 4, 256, 0, stream>>>(sc, nullptr, Pb);
    battn(stream, Pb, vt, nullptr, nullptr, xb, 128, 192, 128, 1.f, 0,
          128, (long)2 * S_ * 128, S_ * 128,
          128, (long)C_ * S_, 192 * S_,
          384, (long)S_ * 384, 192, 2, 64);
    bgemm64(stream, xb, wbC1Wp, ca1_bproj, p, nullptr, B_ * S_, 384, 384, 1.f, 0);
    // 6. ca2
    {
        Ln2Desc d;
        d.X0 = p;    d.g0 = g_q2;  d.b0 = b_q2;  d.Y0 = t1b; d.bf0 = 0; d.rows0 = B_ * S_;
        d.X1 = decb; d.g1 = g_kv2; d.b1 = b_kv2; d.Y1 = t2b; d.bf1 = 1;
        ln2_kernel<<<B_ * S_ + B_ * W_, 128, 0, stream>>>(d);
    }
    {
        GJob js[2];
        js[0] = {t1b, wbC2Wq, nullptr, nullptr, qpb, B_ * S_, 384, 384, rs192, 0};
        js[1] = {t2b, wbC2Wkv, nullptr, nullptr, kvb, B_ * W_, 768, 384, 1.f, 0};
        bgemmJ(stream, 2, js);
    }
    battn(stream, qpb, kvb, nullptr, sc, nullptr, 128, 512, 192, 1.f, 0,
          384, (long)S_ * 384, 192,
          768, (long)W_ * 768, 192,
          512, (long)2 * S_ * 512, S_ * 512, 2, 64,
          kvb, vt, W_);
    softmax_kernel<512, 0><<<(B_ * 2 * S_) / 4, 256, 0, stream>>>(sc, nullptr, Pb);
    battn(stream, Pb, vt, nullptr, nullptr, xb, 128, 192, 512, 1.f, 0,
          512, (long)2 * S_ * 512, S_ * 512,
          512, (long)C_ * W_, 192 * W_,
          384, (long)S_ * 384, 192, 2, 64);
    bgemm64(stream, xb, wbC2Wp, ca2_bproj, p, pb, B_ * S_, 384, 384, 1.f, 0);
    // 7+8. J4: {p_t tanh GEMM, main k/v = dec @ Wkv}
    {
        GJob js[2];
        js[0] = {pb, wbWpw, Wp_b, t1, nullptr, B_ * S_, 384, 384, 1.f, 1};
        js[1] = {decb, wbWkv, nullptr, nullptr, kvb, B_ * W_, 768, 384, 1.f, 0};
        bgemmJ(stream, 2, js);
    }
    pt_kernel<<<B_ * S_, 128, 0, stream>>>(t1, vp_w, vp_b, ptb);
    // 9. main attention: scores (+fused vtrans), gauss-softmax, PV
    battn(stream, qhb, kvb, nullptr, sc, nullptr, 128, 512, 384, 1.f, 0,
          384, (long)S_ * 384, 0,
          768, (long)W_ * 768, 0,
          512, (long)S_ * 512, 0, 1, 32,
          kvb, vt, W_);
    softmax_kernel<512, 1><<<(B_ * S_) / 4, 256, 0, stream>>>(sc, ptb, Pb);
    battn(stream, Pb, vt, nullptr, nullptr, xb, 128, 384, 512, 1.f, 0,
          512, (long)S_ * 512, 0,
          512, (long)C_ * W_, 0,
          384, (long)S_ * 384, 0, 1, 32);
    // 10. out = x @ Wproj + bproj (fp32)
    bgemm64(stream, xb, wbWproj, bproj, out, nullptr, B_ * S_, 384, 384, 1.f, 0);
}